// Round 8
// baseline (3465.500 us; speedup 1.0000x reference)
//
#include <hip/hip_runtime.h>
#include <hip/hip_bf16.h>
#include <hip/hip_fp16.h>

// Problem constants
#define N_PTS_IN   20000
#define CAP0C      540000
#define CAP1C      352000
#define ZD 10
#define YD 200
#define XD 704
#define Z1D 5
#define Y1D 100
#define X1D 352
#define HWOUT (YD*XD)   // 140800

typedef _Float16 f16x8 __attribute__((ext_vector_type(8)));
typedef float    f32x4 __attribute__((ext_vector_type(4)));

// ---------------------------------------------------------------------------
// f_in = sp_feats @ w_in   (20000x64 @ 64x32), f16 output rows
__global__ __launch_bounds__(256) void gemm_in(const float* __restrict__ sp,
                                               const float* __restrict__ w,
                                               __half* __restrict__ fout) {
    int tid = blockIdx.x * 256 + threadIdx.x;
    int row = tid >> 3;
    int c4  = (tid & 7) * 4;
    if (row >= N_PTS_IN) return;
    float4 acc = {0.f, 0.f, 0.f, 0.f};
    const float* sr = sp + (size_t)row * 64;
#pragma unroll
    for (int ci = 0; ci < 64; ci += 4) {
        float4 fv = *(const float4*)(sr + ci);
        const float* wp = w + ci * 32 + c4;
        float4 w0 = *(const float4*)(wp);
        float4 w1 = *(const float4*)(wp + 32);
        float4 w2 = *(const float4*)(wp + 64);
        float4 w3 = *(const float4*)(wp + 96);
        acc.x += fv.x*w0.x + fv.y*w1.x + fv.z*w2.x + fv.w*w3.x;
        acc.y += fv.x*w0.y + fv.y*w1.y + fv.z*w2.y + fv.w*w3.y;
        acc.z += fv.x*w0.z + fv.y*w1.z + fv.z*w2.z + fv.w*w3.z;
        acc.w += fv.x*w0.w + fv.y*w1.w + fv.z*w2.w + fv.w*w3.w;
    }
    __half* fo = fout + (size_t)row * 32 + c4;
    fo[0] = __float2half(acc.x);
    fo[1] = __float2half(acc.y);
    fo[2] = __float2half(acc.z);
    fo[3] = __float2half(acc.w);
}

// ---------------------------------------------------------------------------
// Weight convert+transpose: src f32 [27][CIN][COUT] -> dst f16 [27][COUT][CIN]
__global__ __launch_bounds__(256) void cvt_w(const float* __restrict__ src,
                                             __half* __restrict__ dst,
                                             int CIN, int COUT) {
    int i = blockIdx.x * 256 + threadIdx.x;
    if (i >= 27 * CIN * COUT) return;
    int ci = i % CIN;
    int t  = i / CIN;
    int co = t % COUT;
    int k  = t / COUT;
    dst[i] = __float2half(src[((size_t)k * CIN + ci) * COUT + co]);
}

// ct0_w f32 [320][64] (ci=c*10+z) -> f16 [co][zc=z*32+c]
__global__ __launch_bounds__(256) void cvt_ct0(const float* __restrict__ src,
                                               __half* __restrict__ dst) {
    int i = blockIdx.x * 256 + threadIdx.x;
    if (i >= 64 * 320) return;
    int zc = i % 320, co = i / 320;
    int z = zc >> 5, c = zc & 31;
    dst[i] = __float2half(src[(c * 10 + z) * 64 + co]);
}

// ct1_w f32 [320][64][2][2] (ci=c*5+z) -> f16 [kq][co][zc=z*64+c]
__global__ __launch_bounds__(256) void cvt_ct1(const float* __restrict__ src,
                                               __half* __restrict__ dst) {
    int i = blockIdx.x * 256 + threadIdx.x;
    if (i >= 4 * 64 * 320) return;
    int zc = i % 320;
    int t  = i / 320;
    int co = t & 63;
    int kq = t >> 6;
    int z = zc >> 6, c = zc & 63;
    dst[i] = __float2half(src[((c * 5 + z) * 64 + co) * 4 + kq]);
}

// ---------------------------------------------------------------------------
// Rulebook inversion, TRANSPOSED: nbrT[k*cap + s] = g
__global__ __launch_bounds__(256) void build_nbr(const int* __restrict__ g,
                                                 const int* __restrict__ s,
                                                 int* __restrict__ nbrT,
                                                 int P, int cap) {
    int i = blockIdx.x * 256 + threadIdx.x;
    if (i >= 27 * P) return;
    int k = i / P, p = i - k * P;
    int sv = s[(size_t)k * P + p];
    if (sv >= cap) return;              // dummy pair
    nbrT[(size_t)k * cap + sv] = g[(size_t)k * P + p];
}

// voxel -> sparse-row index (pad coords have z == Zdim, dropped like JAX OOB)
__global__ __launch_bounds__(256) void build_vox(const int* __restrict__ coords,
                                                 int* __restrict__ v2r,
                                                 int cap, int Zdim, int Ydim, int Xdim) {
    int r = blockIdx.x * 256 + threadIdx.x;
    if (r >= cap) return;
    int b = coords[4*r], z = coords[4*r+1], y = coords[4*r+2], x = coords[4*r+3];
    if (z >= Zdim) return;
    v2r[(((size_t)b * Zdim + z) * Ydim + y) * Xdim + x] = r;
}

// ---------------------------------------------------------------------------
// Implicit-GEMM sparse conv via f16 MFMA 16x16x32, + BN + ReLU.
// v4: M-tile=128, rulebook slice in LDS, DOUBLE-BUFFERED LDS A-tile with one
// barrier per k. Gather registers are loaded and consumed within the same
// iteration (never live across a barrier) — R6/R7's cross-barrier prefetch
// plus a launch_bounds min-waves cap made the allocator spill ~800 MB of
// scratch per dispatch (WRITE_SIZE evidence). No 2nd launch_bounds arg.
template <int CIN, int COUT>
__global__ __launch_bounds__(256) void spconv_mfma(const __half* __restrict__ f,
                                                   const __half* __restrict__ wt,
                                                   const float* __restrict__ bnp,
                                                   const int* __restrict__ nbrT,
                                                   __half* __restrict__ fout,
                                                   int ncap) {
    constexpr int NV  = CIN / 16;     // uint4 chunks staged per thread
    constexpr int NCH = CIN / 8;      // 16B chunks per row
    constexpr int SWM = NCH - 1;      // swizzle mask
    constexpr int KT  = CIN / 32;
    constexpr int NT  = COUT / 16;
    constexpr int ABUF = 128 * CIN;                 // halves per A buffer
    constexpr int ASZ2 = 2 * ABUF * 2;              // bytes, double buffer
    constexpr int OSZ  = 128 * COUT * 2;
    constexpr int SMEM = (ASZ2 > OSZ) ? ASZ2 : OSZ;
    __shared__ __align__(16) char smem[SMEM];
    __shared__ int idxL[27 * 128];
    __half* Ah = (__half*)smem;

    int tid = threadIdx.x;
    int m0 = blockIdx.x * 128;
    int wv = tid >> 6, lane = tid & 63;
    int quad = lane >> 4, l16 = lane & 15;

    // staging role: 2 threads per row
    int srow = tid >> 1;               // 0..127
    int shalf = tid & 1;

    // preload this block's rulebook slice (27 x 128), coalesced
    for (int i = tid; i < 27 * 128; i += 256) {
        int r = i & 127;
        int k = i >> 7;
        int grow = m0 + r;
        idxL[i] = (grow < ncap) ? nbrT[(size_t)k * ncap + grow] : -1;
    }
    __syncthreads();

    f32x4 acc[2][NT] = {};

    // prologue: stage k=0 into buffer 0
    {
        int gi = idxL[srow];
#pragma unroll
        for (int j = 0; j < NV; ++j) {
            uint4 z4 = {0u,0u,0u,0u};
            uint4 vv = (gi >= 0) ? ((const uint4*)(f + (size_t)gi * CIN))[shalf * NV + j] : z4;
            int c  = shalf * NV + j;
            int cs = c ^ (srow & SWM);
            *(uint4*)(Ah + srow * CIN + cs * 8) = vv;
        }
    }
    bool anyCur = __syncthreads_or(idxL[srow] >= 0);

#pragma unroll 1
    for (int k = 0; k < 27; ++k) {
        __half* bufC = Ah + (k & 1) * ABUF;
        __half* bufN = Ah + ((k + 1) & 1) * ABUF;
        int gin = (k < 26) ? idxL[(k + 1) * 128 + srow] : -1;
        // issue next tile's gathers (consumed below, same iteration)
        uint4 v[NV];
#pragma unroll
        for (int j = 0; j < NV; ++j) {
            uint4 z4 = {0u,0u,0u,0u};
            v[j] = (gin >= 0) ? ((const uint4*)(f + (size_t)gin * CIN))[shalf * NV + j] : z4;
        }
        // MFMA over current tile (gather latency hides behind this)
        if (anyCur) {
            const __half* wk = wt + (size_t)k * COUT * CIN;
#pragma unroll
            for (int sub = 0; sub < 2; ++sub) {
                int row = wv * 32 + sub * 16 + l16;
#pragma unroll
                for (int kt = 0; kt < KT; ++kt) {
                    int c  = kt * 4 + quad;
                    int cs = c ^ (row & SWM);
                    f16x8 a = *(const f16x8*)(bufC + row * CIN + cs * 8);
#pragma unroll
                    for (int nt = 0; nt < NT; ++nt) {
                        f16x8 b = *(const f16x8*)(wk + (size_t)(nt * 16 + l16) * CIN + kt * 32 + quad * 8);
                        acc[sub][nt] = __builtin_amdgcn_mfma_f32_16x16x32_f16(a, b, acc[sub][nt], 0, 0, 0);
                    }
                }
            }
        }
        // write staged tile into the other buffer (no WAR with bufC reads)
        if (k < 26) {
#pragma unroll
            for (int j = 0; j < NV; ++j) {
                int c  = shalf * NV + j;
                int cs = c ^ (srow & SWM);
                *(uint4*)(bufN + srow * CIN + cs * 8) = v[j];
            }
        }
        // single barrier per k; doubles as the validity or-reduce for k+1
        anyCur = __syncthreads_or(gin >= 0);
    }

    // epilogue: BN + ReLU -> f16 out tile in LDS (A dead) -> coalesced store
    __half* Oh = (__half*)smem;
#pragma unroll
    for (int nt = 0; nt < NT; ++nt) {
        int co = nt * 16 + l16;
        float g = bnp[co], b = bnp[COUT + co];
        float m = bnp[2*COUT + co], vv = bnp[3*COUT + co];
        float s  = g * rsqrtf(vv + 1e-5f);
        float sh = b - m * s;
#pragma unroll
        for (int sub = 0; sub < 2; ++sub) {
#pragma unroll
            for (int r_ = 0; r_ < 4; ++r_) {
                int mrow = wv * 32 + sub * 16 + quad * 4 + r_;
                float val = fmaxf(acc[sub][nt][r_] * s + sh, 0.f);
                Oh[mrow * COUT + co] = __float2half(val);
            }
        }
    }
    __syncthreads();
    constexpr int OCH = COUT / 8;          // 16B chunks per out row
    for (int i = tid; i < 128 * OCH; i += 256) {
        int row = i / OCH, ch = i % OCH;
        int grow = m0 + row;
        if (grow < ncap)
            *(uint4*)(fout + (size_t)grow * COUT + ch * 8) =
                *(const uint4*)(Oh + row * COUT + ch * 8);
    }
}

// ---------------------------------------------------------------------------
// BEV head 0: fused gather + GEMM [64rows x 320] @ [320 x 64] via f16 MFMA,
// + BN + ReLU + 2-agent attention + coalesced store.
__global__ __launch_bounds__(256) void bev0_mfma(const __half* __restrict__ f0,
                                                 const __half* __restrict__ wtT,  // [64][320] zc=z*32+c
                                                 const float* __restrict__ bias,
                                                 const float* __restrict__ bnp,
                                                 const int* __restrict__ v2r,
                                                 float* __restrict__ out) {
    constexpr int AST = 328;
    __shared__ __align__(16) __half Al[64 * AST];   // 41,984 B
    __shared__ float Cl[64][65];                     // wave-private rows
    __shared__ float Ot[64][33];
    int tid = threadIdx.x;
    int y = blockIdx.x / 22, x0 = (blockIdx.x % 22) * 32;
    int wv = tid >> 6, lane = tid & 63;
    int quad = lane >> 4, l16 = lane & 15;

    for (int it = 0; it < 3; ++it) {
        int task = it * 256 + tid;
        if (task < 640) {
            int row = task & 63, z = task >> 6;
            int b = row & 1, p = row >> 1;
            int r = v2r[((b * ZD + z) * YD + y) * XD + x0 + p];
            uint4 v0 = {0,0,0,0}, v1 = {0,0,0,0}, v2 = {0,0,0,0}, v3 = {0,0,0,0};
            if (r >= 0) {
                const uint4* src = (const uint4*)(f0 + (size_t)r * 32);
                v0 = src[0]; v1 = src[1]; v2 = src[2]; v3 = src[3];
            }
            uint4* dst = (uint4*)(Al + row * AST + z * 32);
            dst[0] = v0; dst[1] = v1; dst[2] = v2; dst[3] = v3;
        }
    }
    __syncthreads();

    f32x4 acc[4] = {};
#pragma unroll
    for (int ks = 0; ks < 10; ++ks) {
        f16x8 a = *(const f16x8*)(Al + (wv * 16 + l16) * AST + ks * 32 + quad * 8);
#pragma unroll
        for (int nt = 0; nt < 4; ++nt) {
            f16x8 bfr = *(const f16x8*)(wtT + (size_t)(nt * 16 + l16) * 320 + ks * 32 + quad * 8);
            acc[nt] = __builtin_amdgcn_mfma_f32_16x16x32_f16(a, bfr, acc[nt], 0, 0, 0);
        }
    }
#pragma unroll
    for (int nt = 0; nt < 4; ++nt) {
        int co = nt * 16 + l16;
        float s  = bnp[co] * rsqrtf(bnp[192 + co] + 1e-5f);
        float sh = (bias[co] - bnp[128 + co]) * s + bnp[64 + co];
#pragma unroll
        for (int r_ = 0; r_ < 4; ++r_)
            Cl[wv * 16 + quad * 4 + r_][co] = fmaxf(acc[nt][r_] * s + sh, 0.f);
    }
#pragma unroll
    for (int pi = 0; pi < 8; ++pi) {
        int p = wv * 8 + pi;
        float x0v = Cl[2 * p][lane], x1v = Cl[2 * p + 1][lane];
        float s00 = x0v * x0v, s01 = x0v * x1v;
#pragma unroll
        for (int o = 32; o > 0; o >>= 1) {
            s00 += __shfl_xor(s00, o);
            s01 += __shfl_xor(s01, o);
        }
        float a0 = s00 * 0.125f, a1 = s01 * 0.125f;
        float mx = fmaxf(a0, a1);
        float e0 = expf(a0 - mx), e1 = expf(a1 - mx);
        float inv = 1.f / (e0 + e1);
        Ot[lane][p] = (e0 * x0v + e1 * x1v) * inv;
    }
    __syncthreads();
#pragma unroll
    for (int i = 0; i < 8; ++i) {
        int idx = i * 256 + tid;
        int co = idx >> 5, px = idx & 31;
        out[(size_t)co * HWOUT + (size_t)y * XD + x0 + px] = Ot[co][px];
    }
}

// ---------------------------------------------------------------------------
// BEV head 1: fused gather + 4x (GEMM [64x320]@[320x64]) for the 2x2 s2 convT
// kernel positions + BN + ReLU + attention + coalesced store.
__global__ __launch_bounds__(256) void bev1_mfma(const __half* __restrict__ f1,
                                                 const __half* __restrict__ wtT,  // [4][64][320] zc=z*64+c
                                                 const float* __restrict__ bias,
                                                 const float* __restrict__ bnp,
                                                 const int* __restrict__ v2r,
                                                 float* __restrict__ out) {
    constexpr int AST = 328;
    __shared__ __align__(16) __half Al[64 * AST];
    __shared__ float Cl[64][65];
    __shared__ float Ot[64][65];
    int tid = threadIdx.x;
    int iy = blockIdx.x / 11, j0 = (blockIdx.x % 11) * 32;
    int wv = tid >> 6, lane = tid & 63;
    int quad = lane >> 4, l16 = lane & 15;

    for (int it = 0; it < 3; ++it) {
        int task = it * 256 + tid;
        if (task < 640) {
            int row = task & 63, zh = task >> 6;   // 0..9
            int z = zh >> 1, hf = zh & 1;
            int b = row & 1, p = row >> 1;
            int r = v2r[((b * Z1D + z) * Y1D + iy) * X1D + j0 + p];
            uint4 v0 = {0,0,0,0}, v1 = {0,0,0,0}, v2 = {0,0,0,0}, v3 = {0,0,0,0};
            if (r >= 0) {
                const uint4* src = (const uint4*)(f1 + (size_t)r * 64 + hf * 32);
                v0 = src[0]; v1 = src[1]; v2 = src[2]; v3 = src[3];
            }
            uint4* dst = (uint4*)(Al + row * AST + z * 64 + hf * 32);
            dst[0] = v0; dst[1] = v1; dst[2] = v2; dst[3] = v3;
        }
    }
    __syncthreads();

#pragma unroll 1
    for (int ky = 0; ky < 2; ++ky) {
#pragma unroll 1
        for (int kx = 0; kx < 2; ++kx) {
            const __half* wk = wtT + (size_t)(ky * 2 + kx) * 64 * 320;
            f32x4 acc[4] = {};
#pragma unroll
            for (int ks = 0; ks < 10; ++ks) {
                f16x8 a = *(const f16x8*)(Al + (wv * 16 + l16) * AST + ks * 32 + quad * 8);
#pragma unroll
                for (int nt = 0; nt < 4; ++nt) {
                    f16x8 bfr = *(const f16x8*)(wk + (size_t)(nt * 16 + l16) * 320 + ks * 32 + quad * 8);
                    acc[nt] = __builtin_amdgcn_mfma_f32_16x16x32_f16(a, bfr, acc[nt], 0, 0, 0);
                }
            }
#pragma unroll
            for (int nt = 0; nt < 4; ++nt) {
                int co = nt * 16 + l16;
                float s  = bnp[co] * rsqrtf(bnp[192 + co] + 1e-5f);
                float sh = (bias[co] - bnp[128 + co]) * s + bnp[64 + co];
#pragma unroll
                for (int r_ = 0; r_ < 4; ++r_)
                    Cl[wv * 16 + quad * 4 + r_][co] = fmaxf(acc[nt][r_] * s + sh, 0.f);
            }
#pragma unroll
            for (int pi = 0; pi < 8; ++pi) {
                int p = wv * 8 + pi;
                float x0v = Cl[2 * p][lane], x1v = Cl[2 * p + 1][lane];
                float s00 = x0v * x0v, s01 = x0v * x1v;
#pragma unroll
                for (int o = 32; o > 0; o >>= 1) {
                    s00 += __shfl_xor(s00, o);
                    s01 += __shfl_xor(s01, o);
                }
                float a0 = s00 * 0.125f, a1 = s01 * 0.125f;
                float mx = fmaxf(a0, a1);
                float e0 = expf(a0 - mx), e1 = expf(a1 - mx);
                float inv = 1.f / (e0 + e1);
                Ot[lane][2 * p + kx] = (e0 * x0v + e1 * x1v) * inv;
            }
        }
        __syncthreads();
        int yo = 2 * iy + ky;
#pragma unroll
        for (int i = 0; i < 16; ++i) {
            int idx = i * 256 + tid;
            int co = idx >> 6, xx = idx & 63;
            out[(size_t)co * HWOUT + (size_t)yo * XD + 2 * j0 + xx] = Ot[co][xx];
        }
        __syncthreads();
    }
}

// ---------------------------------------------------------------------------
extern "C" void kernel_launch(void* const* d_in, const int* in_sizes, int n_in,
                              void* d_out, int out_size, void* d_ws, size_t ws_size,
                              hipStream_t stream) {
    const float* sp    = (const float*)d_in[0];
    const float* w_in  = (const float*)d_in[1];
    const float* w0    = (const float*)d_in[2];
    const float* bnp0  = (const float*)d_in[3];
    const float* w0a   = (const float*)d_in[4];
    const float* bnp0a = (const float*)d_in[5];
    const float* w0b   = (const float*)d_in[6];
    const float* bnp0b = (const float*)d_in[7];
    const float* w1    = (const float*)d_in[8];
    const float* bnp1  = (const float*)d_in[9];
    const float* w1a   = (const float*)d_in[10];
    const float* bnp1a = (const float*)d_in[11];
    const float* w1b   = (const float*)d_in[12];
    const float* bnp1b = (const float*)d_in[13];
    const float* ct0w  = (const float*)d_in[14];
    const float* ct0b  = (const float*)d_in[15];
    const float* bnt0  = (const float*)d_in[16];
    const float* ct1w  = (const float*)d_in[17];
    const float* ct1b  = (const float*)d_in[18];
    const float* bnt1  = (const float*)d_in[19];
    const int* coords0 = (const int*)d_in[20];
    const int* coords1 = (const int*)d_in[21];
    const int* g0 = (const int*)d_in[22];
    const int* s0 = (const int*)d_in[23];
    const int* ga = (const int*)d_in[24];
    const int* sa = (const int*)d_in[25];
    const int* g1 = (const int*)d_in[26];
    const int* s1 = (const int*)d_in[27];
    const int* gb = (const int*)d_in[28];
    const int* sb = (const int*)d_in[29];
    float* out = (float*)d_out;

    // -------- workspace carve --------
    __half* fInH = (__half*)d_ws;
    __half* R1h  = fInH + 640000;
    __half* R2h  = R1h + 22528000;
    __half* wt0  = R2h + 22528000;
    __half* wt0a = wt0  + 27648;
    __half* wt0b = wt0a + 27648;
    __half* wt1  = wt0b + 27648;          // [27][64][32]
    __half* wt1a = wt1  + 55296;          // [27][64][64]
    __half* wt1b = wt1a + 110592;
    __half* wtT0 = wt1b + 110592;         // [64][320]
    __half* wtT1 = wtT0 + 20480;          // [4][64][320]
    int*   nbrT = (int*)(wtT1 + 81920);
    int*   v2r0 = nbrT;                          // 2,816,000 ints
    int*   v2r1 = nbrT + 2816000;                //   352,000 ints

    // 0) weight conversion
    cvt_w<<<(27*32*32 + 255) / 256, 256, 0, stream>>>(w0,  wt0,  32, 32);
    cvt_w<<<(27*32*32 + 255) / 256, 256, 0, stream>>>(w0a, wt0a, 32, 32);
    cvt_w<<<(27*32*32 + 255) / 256, 256, 0, stream>>>(w0b, wt0b, 32, 32);
    cvt_w<<<(27*32*64 + 255) / 256, 256, 0, stream>>>(w1,  wt1,  32, 64);
    cvt_w<<<(27*64*64 + 255) / 256, 256, 0, stream>>>(w1a, wt1a, 64, 64);
    cvt_w<<<(27*64*64 + 255) / 256, 256, 0, stream>>>(w1b, wt1b, 64, 64);
    cvt_ct0<<<(64*320 + 255) / 256, 256, 0, stream>>>(ct0w, wtT0);
    cvt_ct1<<<(4*64*320 + 255) / 256, 256, 0, stream>>>(ct1w, wtT1);

    // 1) input channel lift (f16 rows out)
    gemm_in<<<(N_PTS_IN * 8 + 255) / 256, 256, 0, stream>>>(sp, w_in, fInH);

    // 2) conv0 (stride-1 spconv, 32->32): fInH -> R1h
    hipMemsetAsync(nbrT, 0xFF, (size_t)CAP0C * 27 * 4, stream);
    build_nbr<<<(27 * N_PTS_IN + 255) / 256, 256, 0, stream>>>(g0, s0, nbrT, N_PTS_IN, CAP0C);
    spconv_mfma<32, 32><<<(CAP0C + 127) / 128, 256, 0, stream>>>(fInH, wt0, bnp0, nbrT, R1h, CAP0C);

    // 3) subm a/b (32->32), shared rulebook: R1h -> R2h -> R1h
    hipMemsetAsync(nbrT, 0xFF, (size_t)CAP0C * 27 * 4, stream);
    build_nbr<<<(27 * CAP0C + 255) / 256, 256, 0, stream>>>(ga, sa, nbrT, CAP0C, CAP0C);
    spconv_mfma<32, 32><<<(CAP0C + 127) / 128, 256, 0, stream>>>(R1h, wt0a, bnp0a, nbrT, R2h, CAP0C);
    spconv_mfma<32, 32><<<(CAP0C + 127) / 128, 256, 0, stream>>>(R2h, wt0b, bnp0b, nbrT, R1h, CAP0C);

    // 4) BEV head 0 (reads R1h) -> out channels [0,64)
    hipMemsetAsync(v2r0, 0xFF, (size_t)2816000 * 4, stream);
    build_vox<<<(CAP0C + 255) / 256, 256, 0, stream>>>(coords0, v2r0, CAP0C, ZD, YD, XD);
    bev0_mfma<<<YD * 22, 256, 0, stream>>>(R1h, wtT0, ct0b, bnt0, v2r0, out);

    // 5) conv1 (stride-2 spconv, 32->64): R1h -> R2h
    hipMemsetAsync(nbrT, 0xFF, (size_t)CAP1C * 27 * 4, stream);
    build_nbr<<<(27 * CAP0C + 255) / 256, 256, 0, stream>>>(g1, s1, nbrT, CAP0C, CAP1C);
    spconv_mfma<32, 64><<<(CAP1C + 127) / 128, 256, 0, stream>>>(R1h, wt1, bnp1, nbrT, R2h, CAP1C);

    // 6) subm 1a/1b (64->64), shared rulebook: R2h -> R1h -> R2h
    hipMemsetAsync(nbrT, 0xFF, (size_t)CAP1C * 27 * 4, stream);
    build_nbr<<<(27 * CAP1C + 255) / 256, 256, 0, stream>>>(gb, sb, nbrT, CAP1C, CAP1C);
    spconv_mfma<64, 64><<<(CAP1C + 127) / 128, 256, 0, stream>>>(R2h, wt1a, bnp1a, nbrT, R1h, CAP1C);
    spconv_mfma<64, 64><<<(CAP1C + 127) / 128, 256, 0, stream>>>(R1h, wt1b, bnp1b, nbrT, R2h, CAP1C);

    // 7) BEV head 1 (reads R2h) -> out channels [64,128)
    hipMemsetAsync(v2r1, 0xFF, (size_t)352000 * 4, stream);
    build_vox<<<(CAP1C + 255) / 256, 256, 0, stream>>>(coords1, v2r1, CAP1C, Z1D, Y1D, X1D);
    bev1_mfma<<<Y1D * 11, 256, 0, stream>>>(R2h, wtT1, ct1b, bnt1, v2r1, out + (size_t)64 * HWOUT);
}

// Round 9
// 1324.549 us; speedup vs baseline: 2.6164x; 2.6164x over previous
//
#include <hip/hip_runtime.h>
#include <hip/hip_bf16.h>
#include <hip/hip_fp16.h>

// Problem constants
#define N_PTS_IN   20000
#define CAP0C      540000
#define CAP1C      352000
#define ZD 10
#define YD 200
#define XD 704
#define Z1D 5
#define Y1D 100
#define X1D 352
#define HWOUT (YD*XD)   // 140800

typedef _Float16 f16x8 __attribute__((ext_vector_type(8)));
typedef float    f32x4 __attribute__((ext_vector_type(4)));

// ---------------------------------------------------------------------------
// f_in = sp_feats @ w_in   (20000x64 @ 64x32), f16 output rows
__global__ __launch_bounds__(256) void gemm_in(const float* __restrict__ sp,
                                               const float* __restrict__ w,
                                               __half* __restrict__ fout) {
    int tid = blockIdx.x * 256 + threadIdx.x;
    int row = tid >> 3;
    int c4  = (tid & 7) * 4;
    if (row >= N_PTS_IN) return;
    float4 acc = {0.f, 0.f, 0.f, 0.f};
    const float* sr = sp + (size_t)row * 64;
#pragma unroll
    for (int ci = 0; ci < 64; ci += 4) {
        float4 fv = *(const float4*)(sr + ci);
        const float* wp = w + ci * 32 + c4;
        float4 w0 = *(const float4*)(wp);
        float4 w1 = *(const float4*)(wp + 32);
        float4 w2 = *(const float4*)(wp + 64);
        float4 w3 = *(const float4*)(wp + 96);
        acc.x += fv.x*w0.x + fv.y*w1.x + fv.z*w2.x + fv.w*w3.x;
        acc.y += fv.x*w0.y + fv.y*w1.y + fv.z*w2.y + fv.w*w3.y;
        acc.z += fv.x*w0.z + fv.y*w1.z + fv.z*w2.z + fv.w*w3.z;
        acc.w += fv.x*w0.w + fv.y*w1.w + fv.z*w2.w + fv.w*w3.w;
    }
    __half* fo = fout + (size_t)row * 32 + c4;
    fo[0] = __float2half(acc.x);
    fo[1] = __float2half(acc.y);
    fo[2] = __float2half(acc.z);
    fo[3] = __float2half(acc.w);
}

// ---------------------------------------------------------------------------
// Weight convert+transpose: src f32 [27][CIN][COUT] -> dst f16 [27][COUT][CIN]
__global__ __launch_bounds__(256) void cvt_w(const float* __restrict__ src,
                                             __half* __restrict__ dst,
                                             int CIN, int COUT) {
    int i = blockIdx.x * 256 + threadIdx.x;
    if (i >= 27 * CIN * COUT) return;
    int ci = i % CIN;
    int t  = i / CIN;
    int co = t % COUT;
    int k  = t / COUT;
    dst[i] = __float2half(src[((size_t)k * CIN + ci) * COUT + co]);
}

// ct0_w f32 [320][64] (ci=c*10+z) -> f16 [co][zc=z*32+c]
__global__ __launch_bounds__(256) void cvt_ct0(const float* __restrict__ src,
                                               __half* __restrict__ dst) {
    int i = blockIdx.x * 256 + threadIdx.x;
    if (i >= 64 * 320) return;
    int zc = i % 320, co = i / 320;
    int z = zc >> 5, c = zc & 31;
    dst[i] = __float2half(src[(c * 10 + z) * 64 + co]);
}

// ct1_w f32 [320][64][2][2] (ci=c*5+z) -> f16 [kq][co][zc=z*64+c]
__global__ __launch_bounds__(256) void cvt_ct1(const float* __restrict__ src,
                                               __half* __restrict__ dst) {
    int i = blockIdx.x * 256 + threadIdx.x;
    if (i >= 4 * 64 * 320) return;
    int zc = i % 320;
    int t  = i / 320;
    int co = t & 63;
    int kq = t >> 6;
    int z = zc >> 6, c = zc & 63;
    dst[i] = __float2half(src[((c * 5 + z) * 64 + co) * 4 + kq]);
}

// ---------------------------------------------------------------------------
// Rulebook inversion, TRANSPOSED: nbrT[k*cap + s] = g
__global__ __launch_bounds__(256) void build_nbr(const int* __restrict__ g,
                                                 const int* __restrict__ s,
                                                 int* __restrict__ nbrT,
                                                 int P, int cap) {
    int i = blockIdx.x * 256 + threadIdx.x;
    if (i >= 27 * P) return;
    int k = i / P, p = i - k * P;
    int sv = s[(size_t)k * P + p];
    if (sv >= cap) return;              // dummy pair
    nbrT[(size_t)k * cap + sv] = g[(size_t)k * P + p];
}

// voxel -> sparse-row index (pad coords have z == Zdim, dropped like JAX OOB)
__global__ __launch_bounds__(256) void build_vox(const int* __restrict__ coords,
                                                 int* __restrict__ v2r,
                                                 int cap, int Zdim, int Ydim, int Xdim) {
    int r = blockIdx.x * 256 + threadIdx.x;
    if (r >= cap) return;
    int b = coords[4*r], z = coords[4*r+1], y = coords[4*r+2], x = coords[4*r+3];
    if (z >= Zdim) return;
    v2r[(((size_t)b * Zdim + z) * Ydim + y) * Xdim + x] = r;
}

// ---------------------------------------------------------------------------
// Implicit-GEMM sparse conv via f16 MFMA 16x16x32, + BN + ReLU.
// v5: WAVE-AUTONOMOUS. Each wave owns 32 rows x COUT; wave-private LDS
// A-buffer; ZERO __syncthreads in the K-loop (same-wave DS ordering +
// compiler lgkmcnt are sufficient). Latency hidden by TLP across ~7
// independent waves/SIMD instead of intra-block pipelining — R6-R8's
// block-level pipelines all spilled (the allocator pins this kernel at
// ~64 unified VGPRs; acc alone is 32; only R5-style short-lived staging
// registers fit). Wave-ballot skip for dead k. XOR-swizzled A-tile.
template <int CIN, int COUT>
__global__ __launch_bounds__(256) void spconv_wave(const __half* __restrict__ f,
                                                   const __half* __restrict__ wt,
                                                   const float* __restrict__ bnp,
                                                   const int* __restrict__ nbrT,
                                                   __half* __restrict__ fout,
                                                   int ncap) {
    constexpr int NT  = COUT / 16;
    constexpr int KT  = CIN / 32;
    constexpr int NCH = CIN / 8;      // 16B chunks per row
    constexpr int SWM = NCH - 1;      // swizzle mask
    constexpr int NV  = CIN / 16;     // chunks per lane (half a row)
    constexpr int MAXC = (CIN > COUT) ? CIN : COUT;
    __shared__ __align__(16) __half Abuf[4][32 * MAXC];

    int tid = threadIdx.x;
    int wv = tid >> 6, lane = tid & 63;
    int quad = lane >> 4, l16 = lane & 15;
    int row2 = lane >> 1;              // staging row 0..31
    int shalf = lane & 1;
    int m0 = blockIdx.x * 128 + wv * 32;   // wave's first output row
    __half* A = Abuf[wv];

    f32x4 acc[2][NT] = {};
    int rowIdx = m0 + row2;
    bool rowok = rowIdx < ncap;

#pragma unroll 1
    for (int k = 0; k < 27; ++k) {
        int gi = rowok ? nbrT[(size_t)k * ncap + rowIdx] : -1;
        if (__ballot(gi >= 0) == 0ull) continue;     // wave-uniform skip
        // gather + stage (short-lived registers: load -> LDS immediately)
        const uint4* src = (const uint4*)(f + (size_t)((gi < 0) ? 0 : gi) * CIN) + shalf * NV;
#pragma unroll
        for (int j = 0; j < NV; ++j) {
            uint4 vv = {0u, 0u, 0u, 0u};
            if (gi >= 0) vv = src[j];
            int c  = shalf * NV + j;
            int cs = c ^ (row2 & SWM);
            *(uint4*)(A + row2 * CIN + cs * 8) = vv;
        }
        // same-wave DS ordering: no barrier needed before reads
        const __half* wk = wt + (size_t)k * COUT * CIN;
#pragma unroll
        for (int m = 0; m < 2; ++m) {
            int row = m * 16 + l16;
#pragma unroll
            for (int kt = 0; kt < KT; ++kt) {
                int c  = kt * 4 + quad;
                int cs = c ^ (row & SWM);
                f16x8 a = *(const f16x8*)(A + row * CIN + cs * 8);
#pragma unroll
                for (int nt = 0; nt < NT; ++nt) {
                    f16x8 b = *(const f16x8*)(wk + (size_t)(nt * 16 + l16) * CIN + kt * 32 + quad * 8);
                    acc[m][nt] = __builtin_amdgcn_mfma_f32_16x16x32_f16(a, b, acc[m][nt], 0, 0, 0);
                }
            }
        }
    }

    // epilogue: BN + ReLU -> wave-private LDS (A is dead) -> coalesced store.
    // Same-wave DS ordering again: no barrier.
#pragma unroll
    for (int nt = 0; nt < NT; ++nt) {
        int co = nt * 16 + l16;
        float g = bnp[co], b = bnp[COUT + co];
        float mn = bnp[2*COUT + co], vv = bnp[3*COUT + co];
        float s  = g * rsqrtf(vv + 1e-5f);
        float sh = b - mn * s;
#pragma unroll
        for (int m = 0; m < 2; ++m) {
#pragma unroll
            for (int r_ = 0; r_ < 4; ++r_) {
                int mr = m * 16 + quad * 4 + r_;
                A[mr * COUT + co] = __float2half(fmaxf(acc[m][nt][r_] * s + sh, 0.f));
            }
        }
    }
    constexpr int OCH = COUT / 8;              // 16B chunks per out row
    constexpr int OV  = 32 * OCH / 64;         // chunks per lane
#pragma unroll
    for (int j = 0; j < OV; ++j) {
        int idx = j * 64 + lane;
        int r = idx / OCH, c = idx % OCH;
        if (m0 + r < ncap)
            *(uint4*)(fout + (size_t)(m0 + r) * COUT + c * 8) =
                *(const uint4*)(A + r * COUT + c * 8);
    }
}

// ---------------------------------------------------------------------------
// BEV head 0: fused gather + GEMM [64rows x 320] @ [320 x 64] via f16 MFMA,
// + BN + ReLU + 2-agent attention + coalesced store.
__global__ __launch_bounds__(256) void bev0_mfma(const __half* __restrict__ f0,
                                                 const __half* __restrict__ wtT,  // [64][320] zc=z*32+c
                                                 const float* __restrict__ bias,
                                                 const float* __restrict__ bnp,
                                                 const int* __restrict__ v2r,
                                                 float* __restrict__ out) {
    constexpr int AST = 328;
    __shared__ __align__(16) __half Al[64 * AST];   // 41,984 B
    __shared__ float Cl[64][65];                     // wave-private rows
    __shared__ float Ot[64][33];
    int tid = threadIdx.x;
    int y = blockIdx.x / 22, x0 = (blockIdx.x % 22) * 32;
    int wv = tid >> 6, lane = tid & 63;
    int quad = lane >> 4, l16 = lane & 15;

    for (int it = 0; it < 3; ++it) {
        int task = it * 256 + tid;
        if (task < 640) {
            int row = task & 63, z = task >> 6;
            int b = row & 1, p = row >> 1;
            int r = v2r[((b * ZD + z) * YD + y) * XD + x0 + p];
            uint4 v0 = {0,0,0,0}, v1 = {0,0,0,0}, v2 = {0,0,0,0}, v3 = {0,0,0,0};
            if (r >= 0) {
                const uint4* src = (const uint4*)(f0 + (size_t)r * 32);
                v0 = src[0]; v1 = src[1]; v2 = src[2]; v3 = src[3];
            }
            uint4* dst = (uint4*)(Al + row * AST + z * 32);
            dst[0] = v0; dst[1] = v1; dst[2] = v2; dst[3] = v3;
        }
    }
    __syncthreads();

    f32x4 acc[4] = {};
#pragma unroll
    for (int ks = 0; ks < 10; ++ks) {
        f16x8 a = *(const f16x8*)(Al + (wv * 16 + l16) * AST + ks * 32 + quad * 8);
#pragma unroll
        for (int nt = 0; nt < 4; ++nt) {
            f16x8 bfr = *(const f16x8*)(wtT + (size_t)(nt * 16 + l16) * 320 + ks * 32 + quad * 8);
            acc[nt] = __builtin_amdgcn_mfma_f32_16x16x32_f16(a, bfr, acc[nt], 0, 0, 0);
        }
    }
#pragma unroll
    for (int nt = 0; nt < 4; ++nt) {
        int co = nt * 16 + l16;
        float s  = bnp[co] * rsqrtf(bnp[192 + co] + 1e-5f);
        float sh = (bias[co] - bnp[128 + co]) * s + bnp[64 + co];
#pragma unroll
        for (int r_ = 0; r_ < 4; ++r_)
            Cl[wv * 16 + quad * 4 + r_][co] = fmaxf(acc[nt][r_] * s + sh, 0.f);
    }
#pragma unroll
    for (int pi = 0; pi < 8; ++pi) {
        int p = wv * 8 + pi;
        float x0v = Cl[2 * p][lane], x1v = Cl[2 * p + 1][lane];
        float s00 = x0v * x0v, s01 = x0v * x1v;
#pragma unroll
        for (int o = 32; o > 0; o >>= 1) {
            s00 += __shfl_xor(s00, o);
            s01 += __shfl_xor(s01, o);
        }
        float a0 = s00 * 0.125f, a1 = s01 * 0.125f;
        float mx = fmaxf(a0, a1);
        float e0 = expf(a0 - mx), e1 = expf(a1 - mx);
        float inv = 1.f / (e0 + e1);
        Ot[lane][p] = (e0 * x0v + e1 * x1v) * inv;
    }
    __syncthreads();
#pragma unroll
    for (int i = 0; i < 8; ++i) {
        int idx = i * 256 + tid;
        int co = idx >> 5, px = idx & 31;
        out[(size_t)co * HWOUT + (size_t)y * XD + x0 + px] = Ot[co][px];
    }
}

// ---------------------------------------------------------------------------
// BEV head 1: fused gather + 4x (GEMM [64x320]@[320x64]) for the 2x2 s2 convT
// kernel positions + BN + ReLU + attention + coalesced store.
__global__ __launch_bounds__(256) void bev1_mfma(const __half* __restrict__ f1,
                                                 const __half* __restrict__ wtT,  // [4][64][320] zc=z*64+c
                                                 const float* __restrict__ bias,
                                                 const float* __restrict__ bnp,
                                                 const int* __restrict__ v2r,
                                                 float* __restrict__ out) {
    constexpr int AST = 328;
    __shared__ __align__(16) __half Al[64 * AST];
    __shared__ float Cl[64][65];
    __shared__ float Ot[64][65];
    int tid = threadIdx.x;
    int iy = blockIdx.x / 11, j0 = (blockIdx.x % 11) * 32;
    int wv = tid >> 6, lane = tid & 63;
    int quad = lane >> 4, l16 = lane & 15;

    for (int it = 0; it < 3; ++it) {
        int task = it * 256 + tid;
        if (task < 640) {
            int row = task & 63, zh = task >> 6;   // 0..9
            int z = zh >> 1, hf = zh & 1;
            int b = row & 1, p = row >> 1;
            int r = v2r[((b * Z1D + z) * Y1D + iy) * X1D + j0 + p];
            uint4 v0 = {0,0,0,0}, v1 = {0,0,0,0}, v2 = {0,0,0,0}, v3 = {0,0,0,0};
            if (r >= 0) {
                const uint4* src = (const uint4*)(f1 + (size_t)r * 64 + hf * 32);
                v0 = src[0]; v1 = src[1]; v2 = src[2]; v3 = src[3];
            }
            uint4* dst = (uint4*)(Al + row * AST + z * 64 + hf * 32);
            dst[0] = v0; dst[1] = v1; dst[2] = v2; dst[3] = v3;
        }
    }
    __syncthreads();

#pragma unroll 1
    for (int ky = 0; ky < 2; ++ky) {
#pragma unroll 1
        for (int kx = 0; kx < 2; ++kx) {
            const __half* wk = wtT + (size_t)(ky * 2 + kx) * 64 * 320;
            f32x4 acc[4] = {};
#pragma unroll
            for (int ks = 0; ks < 10; ++ks) {
                f16x8 a = *(const f16x8*)(Al + (wv * 16 + l16) * AST + ks * 32 + quad * 8);
#pragma unroll
                for (int nt = 0; nt < 4; ++nt) {
                    f16x8 bfr = *(const f16x8*)(wk + (size_t)(nt * 16 + l16) * 320 + ks * 32 + quad * 8);
                    acc[nt] = __builtin_amdgcn_mfma_f32_16x16x32_f16(a, bfr, acc[nt], 0, 0, 0);
                }
            }
#pragma unroll
            for (int nt = 0; nt < 4; ++nt) {
                int co = nt * 16 + l16;
                float s  = bnp[co] * rsqrtf(bnp[192 + co] + 1e-5f);
                float sh = (bias[co] - bnp[128 + co]) * s + bnp[64 + co];
#pragma unroll
                for (int r_ = 0; r_ < 4; ++r_)
                    Cl[wv * 16 + quad * 4 + r_][co] = fmaxf(acc[nt][r_] * s + sh, 0.f);
            }
#pragma unroll
            for (int pi = 0; pi < 8; ++pi) {
                int p = wv * 8 + pi;
                float x0v = Cl[2 * p][lane], x1v = Cl[2 * p + 1][lane];
                float s00 = x0v * x0v, s01 = x0v * x1v;
#pragma unroll
                for (int o = 32; o > 0; o >>= 1) {
                    s00 += __shfl_xor(s00, o);
                    s01 += __shfl_xor(s01, o);
                }
                float a0 = s00 * 0.125f, a1 = s01 * 0.125f;
                float mx = fmaxf(a0, a1);
                float e0 = expf(a0 - mx), e1 = expf(a1 - mx);
                float inv = 1.f / (e0 + e1);
                Ot[lane][2 * p + kx] = (e0 * x0v + e1 * x1v) * inv;
            }
        }
        __syncthreads();
        int yo = 2 * iy + ky;
#pragma unroll
        for (int i = 0; i < 16; ++i) {
            int idx = i * 256 + tid;
            int co = idx >> 6, xx = idx & 63;
            out[(size_t)co * HWOUT + (size_t)yo * XD + 2 * j0 + xx] = Ot[co][xx];
        }
        __syncthreads();
    }
}

// ---------------------------------------------------------------------------
extern "C" void kernel_launch(void* const* d_in, const int* in_sizes, int n_in,
                              void* d_out, int out_size, void* d_ws, size_t ws_size,
                              hipStream_t stream) {
    const float* sp    = (const float*)d_in[0];
    const float* w_in  = (const float*)d_in[1];
    const float* w0    = (const float*)d_in[2];
    const float* bnp0  = (const float*)d_in[3];
    const float* w0a   = (const float*)d_in[4];
    const float* bnp0a = (const float*)d_in[5];
    const float* w0b   = (const float*)d_in[6];
    const float* bnp0b = (const float*)d_in[7];
    const float* w1    = (const float*)d_in[8];
    const float* bnp1  = (const float*)d_in[9];
    const float* w1a   = (const float*)d_in[10];
    const float* bnp1a = (const float*)d_in[11];
    const float* w1b   = (const float*)d_in[12];
    const float* bnp1b = (const float*)d_in[13];
    const float* ct0w  = (const float*)d_in[14];
    const float* ct0b  = (const float*)d_in[15];
    const float* bnt0  = (const float*)d_in[16];
    const float* ct1w  = (const float*)d_in[17];
    const float* ct1b  = (const float*)d_in[18];
    const float* bnt1  = (const float*)d_in[19];
    const int* coords0 = (const int*)d_in[20];
    const int* coords1 = (const int*)d_in[21];
    const int* g0 = (const int*)d_in[22];
    const int* s0 = (const int*)d_in[23];
    const int* ga = (const int*)d_in[24];
    const int* sa = (const int*)d_in[25];
    const int* g1 = (const int*)d_in[26];
    const int* s1 = (const int*)d_in[27];
    const int* gb = (const int*)d_in[28];
    const int* sb = (const int*)d_in[29];
    float* out = (float*)d_out;

    // -------- workspace carve --------
    __half* fInH = (__half*)d_ws;
    __half* R1h  = fInH + 640000;
    __half* R2h  = R1h + 22528000;
    __half* wt0  = R2h + 22528000;
    __half* wt0a = wt0  + 27648;
    __half* wt0b = wt0a + 27648;
    __half* wt1  = wt0b + 27648;          // [27][64][32]
    __half* wt1a = wt1  + 55296;          // [27][64][64]
    __half* wt1b = wt1a + 110592;
    __half* wtT0 = wt1b + 110592;         // [64][320]
    __half* wtT1 = wtT0 + 20480;          // [4][64][320]
    int*   nbrT = (int*)(wtT1 + 81920);
    int*   v2r0 = nbrT;                          // 2,816,000 ints
    int*   v2r1 = nbrT + 2816000;                //   352,000 ints

    // 0) weight conversion
    cvt_w<<<(27*32*32 + 255) / 256, 256, 0, stream>>>(w0,  wt0,  32, 32);
    cvt_w<<<(27*32*32 + 255) / 256, 256, 0, stream>>>(w0a, wt0a, 32, 32);
    cvt_w<<<(27*32*32 + 255) / 256, 256, 0, stream>>>(w0b, wt0b, 32, 32);
    cvt_w<<<(27*32*64 + 255) / 256, 256, 0, stream>>>(w1,  wt1,  32, 64);
    cvt_w<<<(27*64*64 + 255) / 256, 256, 0, stream>>>(w1a, wt1a, 64, 64);
    cvt_w<<<(27*64*64 + 255) / 256, 256, 0, stream>>>(w1b, wt1b, 64, 64);
    cvt_ct0<<<(64*320 + 255) / 256, 256, 0, stream>>>(ct0w, wtT0);
    cvt_ct1<<<(4*64*320 + 255) / 256, 256, 0, stream>>>(ct1w, wtT1);

    // 1) input channel lift (f16 rows out)
    gemm_in<<<(N_PTS_IN * 8 + 255) / 256, 256, 0, stream>>>(sp, w_in, fInH);

    // 2) conv0 (stride-1 spconv, 32->32): fInH -> R1h
    hipMemsetAsync(nbrT, 0xFF, (size_t)CAP0C * 27 * 4, stream);
    build_nbr<<<(27 * N_PTS_IN + 255) / 256, 256, 0, stream>>>(g0, s0, nbrT, N_PTS_IN, CAP0C);
    spconv_wave<32, 32><<<(CAP0C + 127) / 128, 256, 0, stream>>>(fInH, wt0, bnp0, nbrT, R1h, CAP0C);

    // 3) subm a/b (32->32), shared rulebook: R1h -> R2h -> R1h
    hipMemsetAsync(nbrT, 0xFF, (size_t)CAP0C * 27 * 4, stream);
    build_nbr<<<(27 * CAP0C + 255) / 256, 256, 0, stream>>>(ga, sa, nbrT, CAP0C, CAP0C);
    spconv_wave<32, 32><<<(CAP0C + 127) / 128, 256, 0, stream>>>(R1h, wt0a, bnp0a, nbrT, R2h, CAP0C);
    spconv_wave<32, 32><<<(CAP0C + 127) / 128, 256, 0, stream>>>(R2h, wt0b, bnp0b, nbrT, R1h, CAP0C);

    // 4) BEV head 0 (reads R1h) -> out channels [0,64)
    hipMemsetAsync(v2r0, 0xFF, (size_t)2816000 * 4, stream);
    build_vox<<<(CAP0C + 255) / 256, 256, 0, stream>>>(coords0, v2r0, CAP0C, ZD, YD, XD);
    bev0_mfma<<<YD * 22, 256, 0, stream>>>(R1h, wtT0, ct0b, bnt0, v2r0, out);

    // 5) conv1 (stride-2 spconv, 32->64): R1h -> R2h
    hipMemsetAsync(nbrT, 0xFF, (size_t)CAP1C * 27 * 4, stream);
    build_nbr<<<(27 * CAP0C + 255) / 256, 256, 0, stream>>>(g1, s1, nbrT, CAP0C, CAP1C);
    spconv_wave<32, 64><<<(CAP1C + 127) / 128, 256, 0, stream>>>(R1h, wt1, bnp1, nbrT, R2h, CAP1C);

    // 6) subm 1a/1b (64->64), shared rulebook: R2h -> R1h -> R2h
    hipMemsetAsync(nbrT, 0xFF, (size_t)CAP1C * 27 * 4, stream);
    build_nbr<<<(27 * CAP1C + 255) / 256, 256, 0, stream>>>(gb, sb, nbrT, CAP1C, CAP1C);
    spconv_wave<64, 64><<<(CAP1C + 127) / 128, 256, 0, stream>>>(R2h, wt1a, bnp1a, nbrT, R1h, CAP1C);
    spconv_wave<64, 64><<<(CAP1C + 127) / 128, 256, 0, stream>>>(R1h, wt1b, bnp1b, nbrT, R2h, CAP1C);

    // 7) BEV head 1 (reads R2h) -> out channels [64,128)
    hipMemsetAsync(v2r1, 0xFF, (size_t)352000 * 4, stream);
    build_vox<<<(CAP1C + 255) / 256, 256, 0, stream>>>(coords1, v2r1, CAP1C, Z1D, Y1D, X1D);
    bev1_mfma<<<Y1D * 11, 256, 0, stream>>>(R2h, wtT1, ct1b, bnt1, v2r1, out + (size_t)64 * HWOUT);
}

// Round 10
// 1279.205 us; speedup vs baseline: 2.7091x; 1.0354x over previous
//
#include <hip/hip_runtime.h>
#include <hip/hip_bf16.h>
#include <hip/hip_fp16.h>

// Problem constants
#define N_PTS_IN   20000
#define CAP0C      540000
#define CAP1C      352000
#define ZD 10
#define YD 200
#define XD 704
#define Z1D 5
#define Y1D 100
#define X1D 352
#define HWOUT (YD*XD)   // 140800

typedef _Float16 f16x8 __attribute__((ext_vector_type(8)));
typedef float    f32x4 __attribute__((ext_vector_type(4)));

// ---------------------------------------------------------------------------
// f_in = sp_feats @ w_in   (20000x64 @ 64x32), f16 output rows
__global__ __launch_bounds__(256) void gemm_in(const float* __restrict__ sp,
                                               const float* __restrict__ w,
                                               __half* __restrict__ fout) {
    int tid = blockIdx.x * 256 + threadIdx.x;
    int row = tid >> 3;
    int c4  = (tid & 7) * 4;
    if (row >= N_PTS_IN) return;
    float4 acc = {0.f, 0.f, 0.f, 0.f};
    const float* sr = sp + (size_t)row * 64;
#pragma unroll
    for (int ci = 0; ci < 64; ci += 4) {
        float4 fv = *(const float4*)(sr + ci);
        const float* wp = w + ci * 32 + c4;
        float4 w0 = *(const float4*)(wp);
        float4 w1 = *(const float4*)(wp + 32);
        float4 w2 = *(const float4*)(wp + 64);
        float4 w3 = *(const float4*)(wp + 96);
        acc.x += fv.x*w0.x + fv.y*w1.x + fv.z*w2.x + fv.w*w3.x;
        acc.y += fv.x*w0.y + fv.y*w1.y + fv.z*w2.y + fv.w*w3.y;
        acc.z += fv.x*w0.z + fv.y*w1.z + fv.z*w2.z + fv.w*w3.z;
        acc.w += fv.x*w0.w + fv.y*w1.w + fv.z*w2.w + fv.w*w3.w;
    }
    __half* fo = fout + (size_t)row * 32 + c4;
    fo[0] = __float2half(acc.x);
    fo[1] = __float2half(acc.y);
    fo[2] = __float2half(acc.z);
    fo[3] = __float2half(acc.w);
}

// ---------------------------------------------------------------------------
// Weight convert+transpose: src f32 [27][CIN][COUT] -> dst f16 [27][COUT][CIN]
__global__ __launch_bounds__(256) void cvt_w(const float* __restrict__ src,
                                             __half* __restrict__ dst,
                                             int CIN, int COUT) {
    int i = blockIdx.x * 256 + threadIdx.x;
    if (i >= 27 * CIN * COUT) return;
    int ci = i % CIN;
    int t  = i / CIN;
    int co = t % COUT;
    int k  = t / COUT;
    dst[i] = __float2half(src[((size_t)k * CIN + ci) * COUT + co]);
}

// ct0_w f32 [320][64] (ci=c*10+z) -> f16 [co][zc=z*32+c]
__global__ __launch_bounds__(256) void cvt_ct0(const float* __restrict__ src,
                                               __half* __restrict__ dst) {
    int i = blockIdx.x * 256 + threadIdx.x;
    if (i >= 64 * 320) return;
    int zc = i % 320, co = i / 320;
    int z = zc >> 5, c = zc & 31;
    dst[i] = __float2half(src[(c * 10 + z) * 64 + co]);
}

// ct1_w f32 [320][64][2][2] (ci=c*5+z) -> f16 [kq][co][zc=z*64+c]
__global__ __launch_bounds__(256) void cvt_ct1(const float* __restrict__ src,
                                               __half* __restrict__ dst) {
    int i = blockIdx.x * 256 + threadIdx.x;
    if (i >= 4 * 64 * 320) return;
    int zc = i % 320;
    int t  = i / 320;
    int co = t & 63;
    int kq = t >> 6;
    int z = zc >> 6, c = zc & 63;
    dst[i] = __float2half(src[((c * 5 + z) * 64 + co) * 4 + kq]);
}

// ---------------------------------------------------------------------------
// Rulebook inversion, TRANSPOSED: nbrT[k*cap + s] = g
__global__ __launch_bounds__(256) void build_nbr(const int* __restrict__ g,
                                                 const int* __restrict__ s,
                                                 int* __restrict__ nbrT,
                                                 int P, int cap) {
    int i = blockIdx.x * 256 + threadIdx.x;
    if (i >= 27 * P) return;
    int k = i / P, p = i - k * P;
    int sv = s[(size_t)k * P + p];
    if (sv >= cap) return;              // dummy pair
    nbrT[(size_t)k * cap + sv] = g[(size_t)k * P + p];
}

// voxel -> sparse-row index (pad coords have z == Zdim, dropped like JAX OOB)
__global__ __launch_bounds__(256) void build_vox(const int* __restrict__ coords,
                                                 int* __restrict__ v2r,
                                                 int cap, int Zdim, int Ydim, int Xdim) {
    int r = blockIdx.x * 256 + threadIdx.x;
    if (r >= cap) return;
    int b = coords[4*r], z = coords[4*r+1], y = coords[4*r+2], x = coords[4*r+3];
    if (z >= Zdim) return;
    v2r[(((size_t)b * Zdim + z) * Ydim + y) * Xdim + x] = r;
}

// ---------------------------------------------------------------------------
// Implicit-GEMM sparse conv via f16 MFMA 16x16x32, + BN + ReLU.
// v6: wave-autonomous (R9) + in-wave software pipeline:
//   - index prefetch depth 2 (nbr latency off the ballot critical path)
//   - feature prefetch depth 1 into registers + wave-private LDS DOUBLE buffer
//     (feature latency hides behind the previous k's ds_read+MFMA section)
// Still ZERO barriers -> no cross-convergence register state -> no spill
// (R6-R8 lesson). Prefetch regs (vn: 16 VGPR @CIN=64) live only across the
// MFMA section. Wave-ballot skip for dead k still works (decision known one
// iteration early).
template <int CIN, int COUT>
__global__ __launch_bounds__(256) void spconv_wave(const __half* __restrict__ f,
                                                   const __half* __restrict__ wt,
                                                   const float* __restrict__ bnp,
                                                   const int* __restrict__ nbrT,
                                                   __half* __restrict__ fout,
                                                   int ncap) {
    constexpr int NT  = COUT / 16;
    constexpr int KT  = CIN / 32;
    constexpr int NCH = CIN / 8;      // 16B chunks per row
    constexpr int SWM = NCH - 1;      // swizzle mask
    constexpr int NV  = CIN / 16;     // chunks per lane (half a row)
    constexpr int ABUF = 32 * CIN;    // halves per A buffer
    constexpr int WLDS = (2 * ABUF > 32 * COUT) ? 2 * ABUF : 32 * COUT;
    __shared__ __align__(16) __half Abuf[4][WLDS];

    int tid = threadIdx.x;
    int wv = tid >> 6, lane = tid & 63;
    int quad = lane >> 4, l16 = lane & 15;
    int row2 = lane >> 1;              // staging row 0..31
    int shalf = lane & 1;
    int m0 = blockIdx.x * 128 + wv * 32;   // wave's first output row
    __half* A = Abuf[wv];

    f32x4 acc[2][NT] = {};
    int rowIdx = m0 + row2;
    bool rowok = rowIdx < ncap;

    // index pipeline: current k and k+1
    int giC = rowok ? nbrT[rowIdx] : -1;                      // k = 0
    int giN = rowok ? nbrT[(size_t)ncap + rowIdx] : -1;       // k = 1
    bool anyC = __ballot(giC >= 0) != 0ull;
    int p = 0;
    if (anyC) {   // prologue: stage k=0 into buffer 0 (synchronous, once)
        const uint4* s0 = (const uint4*)(f + (size_t)((giC < 0) ? 0 : giC) * CIN) + shalf * NV;
#pragma unroll
        for (int j = 0; j < NV; ++j) {
            uint4 vv = {0u,0u,0u,0u};
            if (giC >= 0) vv = s0[j];
            int c  = shalf * NV + j;
            int cs = c ^ (row2 & SWM);
            *(uint4*)(A + row2 * CIN + cs * 8) = vv;
        }
    }

#pragma unroll 1
    for (int k = 0; k < 27; ++k) {
        // issue index load for k+2 (consumed next iteration)
        int giNN = (k + 2 < 27 && rowok) ? nbrT[(size_t)(k + 2) * ncap + rowIdx] : -1;
        bool anyN = __ballot(giN >= 0) != 0ull;
        // prefetch features for k+1 into registers (issued before MFMA)
        uint4 vn[NV];
        if (anyN) {
            const uint4* sn = (const uint4*)(f + (size_t)((giN < 0) ? 0 : giN) * CIN) + shalf * NV;
#pragma unroll
            for (int j = 0; j < NV; ++j) {
                uint4 vv = {0u,0u,0u,0u};
                if (giN >= 0) vv = sn[j];
                vn[j] = vv;
            }
        }
        // MFMA on current tile (covers the vn load latency)
        if (anyC) {
            const __half* wk = wt + (size_t)k * COUT * CIN;
            const __half* Ab = A + p * ABUF;
#pragma unroll
            for (int m = 0; m < 2; ++m) {
                int row = m * 16 + l16;
#pragma unroll
                for (int kt = 0; kt < KT; ++kt) {
                    int c  = kt * 4 + quad;
                    int cs = c ^ (row & SWM);
                    f16x8 a = *(const f16x8*)(Ab + row * CIN + cs * 8);
#pragma unroll
                    for (int nt = 0; nt < NT; ++nt) {
                        f16x8 b = *(const f16x8*)(wk + (size_t)(nt * 16 + l16) * CIN + kt * 32 + quad * 8);
                        acc[m][nt] = __builtin_amdgcn_mfma_f32_16x16x32_f16(a, b, acc[m][nt], 0, 0, 0);
                    }
                }
            }
        }
        // stage k+1 into the other buffer (same-wave DS ordering, no barrier)
        if (anyN) {
            int pn = p ^ 1;
#pragma unroll
            for (int j = 0; j < NV; ++j) {
                int c  = shalf * NV + j;
                int cs = c ^ (row2 & SWM);
                *(uint4*)(A + pn * ABUF + row2 * CIN + cs * 8) = vn[j];
            }
            p = pn;
        }
        anyC = anyN;
        giN = giNN;
    }

    // epilogue: BN + ReLU -> wave-private LDS (A dead) -> coalesced store.
#pragma unroll
    for (int nt = 0; nt < NT; ++nt) {
        int co = nt * 16 + l16;
        float g = bnp[co], b = bnp[COUT + co];
        float mn = bnp[2*COUT + co], vv = bnp[3*COUT + co];
        float s  = g * rsqrtf(vv + 1e-5f);
        float sh = b - mn * s;
#pragma unroll
        for (int m = 0; m < 2; ++m) {
#pragma unroll
            for (int r_ = 0; r_ < 4; ++r_) {
                int mr = m * 16 + quad * 4 + r_;
                A[mr * COUT + co] = __float2half(fmaxf(acc[m][nt][r_] * s + sh, 0.f));
            }
        }
    }
    constexpr int OCH = COUT / 8;              // 16B chunks per out row
    constexpr int OV  = 32 * OCH / 64;         // chunks per lane
#pragma unroll
    for (int j = 0; j < OV; ++j) {
        int idx = j * 64 + lane;
        int r = idx / OCH, c = idx % OCH;
        if (m0 + r < ncap)
            *(uint4*)(fout + (size_t)(m0 + r) * COUT + c * 8) =
                *(const uint4*)(A + r * COUT + c * 8);
    }
}

// ---------------------------------------------------------------------------
// BEV head 0: fused gather + GEMM [64rows x 320] @ [320 x 64] via f16 MFMA,
// + BN + ReLU + 2-agent attention + coalesced store.
__global__ __launch_bounds__(256) void bev0_mfma(const __half* __restrict__ f0,
                                                 const __half* __restrict__ wtT,  // [64][320] zc=z*32+c
                                                 const float* __restrict__ bias,
                                                 const float* __restrict__ bnp,
                                                 const int* __restrict__ v2r,
                                                 float* __restrict__ out) {
    constexpr int AST = 328;
    __shared__ __align__(16) __half Al[64 * AST];   // 41,984 B
    __shared__ float Cl[64][65];                     // wave-private rows
    __shared__ float Ot[64][33];
    int tid = threadIdx.x;
    int y = blockIdx.x / 22, x0 = (blockIdx.x % 22) * 32;
    int wv = tid >> 6, lane = tid & 63;
    int quad = lane >> 4, l16 = lane & 15;

    for (int it = 0; it < 3; ++it) {
        int task = it * 256 + tid;
        if (task < 640) {
            int row = task & 63, z = task >> 6;
            int b = row & 1, p = row >> 1;
            int r = v2r[((b * ZD + z) * YD + y) * XD + x0 + p];
            uint4 v0 = {0,0,0,0}, v1 = {0,0,0,0}, v2 = {0,0,0,0}, v3 = {0,0,0,0};
            if (r >= 0) {
                const uint4* src = (const uint4*)(f0 + (size_t)r * 32);
                v0 = src[0]; v1 = src[1]; v2 = src[2]; v3 = src[3];
            }
            uint4* dst = (uint4*)(Al + row * AST + z * 32);
            dst[0] = v0; dst[1] = v1; dst[2] = v2; dst[3] = v3;
        }
    }
    __syncthreads();

    f32x4 acc[4] = {};
#pragma unroll
    for (int ks = 0; ks < 10; ++ks) {
        f16x8 a = *(const f16x8*)(Al + (wv * 16 + l16) * AST + ks * 32 + quad * 8);
#pragma unroll
        for (int nt = 0; nt < 4; ++nt) {
            f16x8 bfr = *(const f16x8*)(wtT + (size_t)(nt * 16 + l16) * 320 + ks * 32 + quad * 8);
            acc[nt] = __builtin_amdgcn_mfma_f32_16x16x32_f16(a, bfr, acc[nt], 0, 0, 0);
        }
    }
#pragma unroll
    for (int nt = 0; nt < 4; ++nt) {
        int co = nt * 16 + l16;
        float s  = bnp[co] * rsqrtf(bnp[192 + co] + 1e-5f);
        float sh = (bias[co] - bnp[128 + co]) * s + bnp[64 + co];
#pragma unroll
        for (int r_ = 0; r_ < 4; ++r_)
            Cl[wv * 16 + quad * 4 + r_][co] = fmaxf(acc[nt][r_] * s + sh, 0.f);
    }
#pragma unroll
    for (int pi = 0; pi < 8; ++pi) {
        int p = wv * 8 + pi;
        float x0v = Cl[2 * p][lane], x1v = Cl[2 * p + 1][lane];
        float s00 = x0v * x0v, s01 = x0v * x1v;
#pragma unroll
        for (int o = 32; o > 0; o >>= 1) {
            s00 += __shfl_xor(s00, o);
            s01 += __shfl_xor(s01, o);
        }
        float a0 = s00 * 0.125f, a1 = s01 * 0.125f;
        float mx = fmaxf(a0, a1);
        float e0 = expf(a0 - mx), e1 = expf(a1 - mx);
        float inv = 1.f / (e0 + e1);
        Ot[lane][p] = (e0 * x0v + e1 * x1v) * inv;
    }
    __syncthreads();
#pragma unroll
    for (int i = 0; i < 8; ++i) {
        int idx = i * 256 + tid;
        int co = idx >> 5, px = idx & 31;
        out[(size_t)co * HWOUT + (size_t)y * XD + x0 + px] = Ot[co][px];
    }
}

// ---------------------------------------------------------------------------
// BEV head 1: fused gather + 4x (GEMM [64x320]@[320x64]) for the 2x2 s2 convT
// kernel positions + BN + ReLU + attention + coalesced store.
__global__ __launch_bounds__(256) void bev1_mfma(const __half* __restrict__ f1,
                                                 const __half* __restrict__ wtT,  // [4][64][320] zc=z*64+c
                                                 const float* __restrict__ bias,
                                                 const float* __restrict__ bnp,
                                                 const int* __restrict__ v2r,
                                                 float* __restrict__ out) {
    constexpr int AST = 328;
    __shared__ __align__(16) __half Al[64 * AST];
    __shared__ float Cl[64][65];
    __shared__ float Ot[64][65];
    int tid = threadIdx.x;
    int iy = blockIdx.x / 11, j0 = (blockIdx.x % 11) * 32;
    int wv = tid >> 6, lane = tid & 63;
    int quad = lane >> 4, l16 = lane & 15;

    for (int it = 0; it < 3; ++it) {
        int task = it * 256 + tid;
        if (task < 640) {
            int row = task & 63, zh = task >> 6;   // 0..9
            int z = zh >> 1, hf = zh & 1;
            int b = row & 1, p = row >> 1;
            int r = v2r[((b * Z1D + z) * Y1D + iy) * X1D + j0 + p];
            uint4 v0 = {0,0,0,0}, v1 = {0,0,0,0}, v2 = {0,0,0,0}, v3 = {0,0,0,0};
            if (r >= 0) {
                const uint4* src = (const uint4*)(f1 + (size_t)r * 64 + hf * 32);
                v0 = src[0]; v1 = src[1]; v2 = src[2]; v3 = src[3];
            }
            uint4* dst = (uint4*)(Al + row * AST + z * 64 + hf * 32);
            dst[0] = v0; dst[1] = v1; dst[2] = v2; dst[3] = v3;
        }
    }
    __syncthreads();

#pragma unroll 1
    for (int ky = 0; ky < 2; ++ky) {
#pragma unroll 1
        for (int kx = 0; kx < 2; ++kx) {
            const __half* wk = wtT + (size_t)(ky * 2 + kx) * 64 * 320;
            f32x4 acc[4] = {};
#pragma unroll
            for (int ks = 0; ks < 10; ++ks) {
                f16x8 a = *(const f16x8*)(Al + (wv * 16 + l16) * AST + ks * 32 + quad * 8);
#pragma unroll
                for (int nt = 0; nt < 4; ++nt) {
                    f16x8 bfr = *(const f16x8*)(wk + (size_t)(nt * 16 + l16) * 320 + ks * 32 + quad * 8);
                    acc[nt] = __builtin_amdgcn_mfma_f32_16x16x32_f16(a, bfr, acc[nt], 0, 0, 0);
                }
            }
#pragma unroll
            for (int nt = 0; nt < 4; ++nt) {
                int co = nt * 16 + l16;
                float s  = bnp[co] * rsqrtf(bnp[192 + co] + 1e-5f);
                float sh = (bias[co] - bnp[128 + co]) * s + bnp[64 + co];
#pragma unroll
                for (int r_ = 0; r_ < 4; ++r_)
                    Cl[wv * 16 + quad * 4 + r_][co] = fmaxf(acc[nt][r_] * s + sh, 0.f);
            }
#pragma unroll
            for (int pi = 0; pi < 8; ++pi) {
                int p = wv * 8 + pi;
                float x0v = Cl[2 * p][lane], x1v = Cl[2 * p + 1][lane];
                float s00 = x0v * x0v, s01 = x0v * x1v;
#pragma unroll
                for (int o = 32; o > 0; o >>= 1) {
                    s00 += __shfl_xor(s00, o);
                    s01 += __shfl_xor(s01, o);
                }
                float a0 = s00 * 0.125f, a1 = s01 * 0.125f;
                float mx = fmaxf(a0, a1);
                float e0 = expf(a0 - mx), e1 = expf(a1 - mx);
                float inv = 1.f / (e0 + e1);
                Ot[lane][2 * p + kx] = (e0 * x0v + e1 * x1v) * inv;
            }
        }
        __syncthreads();
        int yo = 2 * iy + ky;
#pragma unroll
        for (int i = 0; i < 16; ++i) {
            int idx = i * 256 + tid;
            int co = idx >> 6, xx = idx & 63;
            out[(size_t)co * HWOUT + (size_t)yo * XD + 2 * j0 + xx] = Ot[co][xx];
        }
        __syncthreads();
    }
}

// ---------------------------------------------------------------------------
extern "C" void kernel_launch(void* const* d_in, const int* in_sizes, int n_in,
                              void* d_out, int out_size, void* d_ws, size_t ws_size,
                              hipStream_t stream) {
    const float* sp    = (const float*)d_in[0];
    const float* w_in  = (const float*)d_in[1];
    const float* w0    = (const float*)d_in[2];
    const float* bnp0  = (const float*)d_in[3];
    const float* w0a   = (const float*)d_in[4];
    const float* bnp0a = (const float*)d_in[5];
    const float* w0b   = (const float*)d_in[6];
    const float* bnp0b = (const float*)d_in[7];
    const float* w1    = (const float*)d_in[8];
    const float* bnp1  = (const float*)d_in[9];
    const float* w1a   = (const float*)d_in[10];
    const float* bnp1a = (const float*)d_in[11];
    const float* w1b   = (const float*)d_in[12];
    const float* bnp1b = (const float*)d_in[13];
    const float* ct0w  = (const float*)d_in[14];
    const float* ct0b  = (const float*)d_in[15];
    const float* bnt0  = (const float*)d_in[16];
    const float* ct1w  = (const float*)d_in[17];
    const float* ct1b  = (const float*)d_in[18];
    const float* bnt1  = (const float*)d_in[19];
    const int* coords0 = (const int*)d_in[20];
    const int* coords1 = (const int*)d_in[21];
    const int* g0 = (const int*)d_in[22];
    const int* s0 = (const int*)d_in[23];
    const int* ga = (const int*)d_in[24];
    const int* sa = (const int*)d_in[25];
    const int* g1 = (const int*)d_in[26];
    const int* s1 = (const int*)d_in[27];
    const int* gb = (const int*)d_in[28];
    const int* sb = (const int*)d_in[29];
    float* out = (float*)d_out;

    // -------- workspace carve --------
    __half* fInH = (__half*)d_ws;
    __half* R1h  = fInH + 640000;
    __half* R2h  = R1h + 22528000;
    __half* wt0  = R2h + 22528000;
    __half* wt0a = wt0  + 27648;
    __half* wt0b = wt0a + 27648;
    __half* wt1  = wt0b + 27648;          // [27][64][32]
    __half* wt1a = wt1  + 55296;          // [27][64][64]
    __half* wt1b = wt1a + 110592;
    __half* wtT0 = wt1b + 110592;         // [64][320]
    __half* wtT1 = wtT0 + 20480;          // [4][64][320]
    int*   nbrT = (int*)(wtT1 + 81920);
    int*   v2r0 = nbrT;                          // 2,816,000 ints
    int*   v2r1 = nbrT + 2816000;                //   352,000 ints

    // 0) weight conversion
    cvt_w<<<(27*32*32 + 255) / 256, 256, 0, stream>>>(w0,  wt0,  32, 32);
    cvt_w<<<(27*32*32 + 255) / 256, 256, 0, stream>>>(w0a, wt0a, 32, 32);
    cvt_w<<<(27*32*32 + 255) / 256, 256, 0, stream>>>(w0b, wt0b, 32, 32);
    cvt_w<<<(27*32*64 + 255) / 256, 256, 0, stream>>>(w1,  wt1,  32, 64);
    cvt_w<<<(27*64*64 + 255) / 256, 256, 0, stream>>>(w1a, wt1a, 64, 64);
    cvt_w<<<(27*64*64 + 255) / 256, 256, 0, stream>>>(w1b, wt1b, 64, 64);
    cvt_ct0<<<(64*320 + 255) / 256, 256, 0, stream>>>(ct0w, wtT0);
    cvt_ct1<<<(4*64*320 + 255) / 256, 256, 0, stream>>>(ct1w, wtT1);

    // 1) input channel lift (f16 rows out)
    gemm_in<<<(N_PTS_IN * 8 + 255) / 256, 256, 0, stream>>>(sp, w_in, fInH);

    // 2) conv0 (stride-1 spconv, 32->32): fInH -> R1h
    hipMemsetAsync(nbrT, 0xFF, (size_t)CAP0C * 27 * 4, stream);
    build_nbr<<<(27 * N_PTS_IN + 255) / 256, 256, 0, stream>>>(g0, s0, nbrT, N_PTS_IN, CAP0C);
    spconv_wave<32, 32><<<(CAP0C + 127) / 128, 256, 0, stream>>>(fInH, wt0, bnp0, nbrT, R1h, CAP0C);

    // 3) subm a/b (32->32), shared rulebook: R1h -> R2h -> R1h
    hipMemsetAsync(nbrT, 0xFF, (size_t)CAP0C * 27 * 4, stream);
    build_nbr<<<(27 * CAP0C + 255) / 256, 256, 0, stream>>>(ga, sa, nbrT, CAP0C, CAP0C);
    spconv_wave<32, 32><<<(CAP0C + 127) / 128, 256, 0, stream>>>(R1h, wt0a, bnp0a, nbrT, R2h, CAP0C);
    spconv_wave<32, 32><<<(CAP0C + 127) / 128, 256, 0, stream>>>(R2h, wt0b, bnp0b, nbrT, R1h, CAP0C);

    // 4) BEV head 0 (reads R1h) -> out channels [0,64)
    hipMemsetAsync(v2r0, 0xFF, (size_t)2816000 * 4, stream);
    build_vox<<<(CAP0C + 255) / 256, 256, 0, stream>>>(coords0, v2r0, CAP0C, ZD, YD, XD);
    bev0_mfma<<<YD * 22, 256, 0, stream>>>(R1h, wtT0, ct0b, bnt0, v2r0, out);

    // 5) conv1 (stride-2 spconv, 32->64): R1h -> R2h
    hipMemsetAsync(nbrT, 0xFF, (size_t)CAP1C * 27 * 4, stream);
    build_nbr<<<(27 * CAP0C + 255) / 256, 256, 0, stream>>>(g1, s1, nbrT, CAP0C, CAP1C);
    spconv_wave<32, 64><<<(CAP1C + 127) / 128, 256, 0, stream>>>(R1h, wt1, bnp1, nbrT, R2h, CAP1C);

    // 6) subm 1a/1b (64->64), shared rulebook: R2h -> R1h -> R2h
    hipMemsetAsync(nbrT, 0xFF, (size_t)CAP1C * 27 * 4, stream);
    build_nbr<<<(27 * CAP1C + 255) / 256, 256, 0, stream>>>(gb, sb, nbrT, CAP1C, CAP1C);
    spconv_wave<64, 64><<<(CAP1C + 127) / 128, 256, 0, stream>>>(R2h, wt1a, bnp1a, nbrT, R1h, CAP1C);
    spconv_wave<64, 64><<<(CAP1C + 127) / 128, 256, 0, stream>>>(R1h, wt1b, bnp1b, nbrT, R2h, CAP1C);

    // 7) BEV head 1 (reads R2h) -> out channels [64,128)
    hipMemsetAsync(v2r1, 0xFF, (size_t)352000 * 4, stream);
    build_vox<<<(CAP1C + 255) / 256, 256, 0, stream>>>(coords1, v2r1, CAP1C, Z1D, Y1D, X1D);
    bev1_mfma<<<Y1D * 11, 256, 0, stream>>>(R2h, wtT1, ct1b, bnt1, v2r1, out + (size_t)64 * HWOUT);
}